// Round 10
// baseline (626.119 us; speedup 1.0000x reference)
//
#include <hip/hip_runtime.h>

#define BK_SHIFT 7
#define NB_MAX 1024
#define CHUNK 8192

// ---------------- Bucketed edge staging (no global atomics) ----------------

// Pass A: per-block bucket histogram (bucket = dst >> 7), int4-vectorized.
__global__ __launch_bounds__(256) void k_bucket_count(const int* __restrict__ dst,
                                                      int* __restrict__ blkcnt,
                                                      int E, int NB, int NBLK) {
  __shared__ int cnt[NB_MAX];
  int t = threadIdx.x, b = blockIdx.x;
  for (int i = t; i < NB; i += 256) cnt[i] = 0;
  __syncthreads();
  int e0 = b * CHUNK, e1 = min(E, e0 + CHUNK);
  if (e1 - e0 == CHUNK) {
    const int4* d4 = (const int4*)(dst + e0);
#pragma unroll 2
    for (int i = t; i < CHUNK / 4; i += 256) {
      int4 v = d4[i];
      atomicAdd(&cnt[v.x >> BK_SHIFT], 1);
      atomicAdd(&cnt[v.y >> BK_SHIFT], 1);
      atomicAdd(&cnt[v.z >> BK_SHIFT], 1);
      atomicAdd(&cnt[v.w >> BK_SHIFT], 1);
    }
  } else {
    for (int e = e0 + t; e < e1; e += 256) atomicAdd(&cnt[dst[e] >> BK_SHIFT], 1);
  }
  __syncthreads();
  for (int i = t; i < NB; i += 256) blkcnt[(size_t)i * NBLK + b] = cnt[i];
}

// Pass B: per-bucket exclusive scan across blocks (in place), bucket totals out.
__global__ __launch_bounds__(256) void k_bucket_scanB(int* __restrict__ blkcnt,
                                                      int* __restrict__ btot, int NBLK) {
  __shared__ int v[256];
  int t = threadIdx.x, k = blockIdx.x;
  int x = (t < NBLK) ? blkcnt[(size_t)k * NBLK + t] : 0;
  v[t] = x;
  __syncthreads();
  for (int off = 1; off < 256; off <<= 1) {
    int u = (t >= off) ? v[t - off] : 0;
    __syncthreads();
    v[t] += u;
    __syncthreads();
  }
  if (t < NBLK) blkcnt[(size_t)k * NBLK + t] = v[t] - x;  // exclusive
  if (t == 255) btot[k] = v[255];
}

// Pass B2: exclusive scan over bucket totals -> bucket base offsets
__global__ __launch_bounds__(1024) void k_bucket_base(const int* __restrict__ btot,
                                                      int* __restrict__ bbase, int NB) {
  __shared__ int v[1024];
  int t = threadIdx.x;
  int x = (t < NB) ? btot[t] : 0;
  v[t] = x;
  __syncthreads();
  for (int off = 1; off < 1024; off <<= 1) {
    int u = (t >= off) ? v[t - off] : 0;
    __syncthreads();
    v[t] += u;
    __syncthreads();
  }
  if (t < NB) bbase[t] = v[t] - x;
  if (t == 1023) bbase[NB] = v[1023];
}

// Pass C: scatter packed (dlow<<25)|src into bucket-contiguous staging, LDS cursors
__global__ __launch_bounds__(256) void k_bucket_scatter(const int* __restrict__ src,
                                                        const int* __restrict__ dst,
                                                        const int* __restrict__ blkoff,
                                                        const int* __restrict__ bbase,
                                                        unsigned* __restrict__ staging,
                                                        int E, int NB, int NBLK) {
  __shared__ int curs[NB_MAX];
  int t = threadIdx.x, b = blockIdx.x;
  for (int i = t; i < NB; i += 256) curs[i] = bbase[i] + blkoff[(size_t)i * NBLK + b];
  __syncthreads();
  int e0 = b * CHUNK, e1 = min(E, e0 + CHUNK);
  for (int e = e0 + t; e < e1; e += 256) {
    int d = dst[e], s = src[e];
    int slot = atomicAdd(&curs[d >> BK_SHIFT], 1);
    staging[slot] = ((unsigned)(d & 127) << 25) | (unsigned)s;
  }
}

// Pass D (tiny): per-bucket node degree -> dinv only (no col build).
__global__ __launch_bounds__(256) void k_deg(const unsigned* __restrict__ staging,
                                             const int* __restrict__ bbase,
                                             float* __restrict__ dinv, int N) {
  __shared__ int cnt[128];
  int t = threadIdx.x, k = blockIdx.x;
  int node0 = k << BK_SHIFT;
  if (t < 128) cnt[t] = 0;
  __syncthreads();
  int e0 = bbase[k], e1 = bbase[k + 1];
  for (int e = e0 + t; e < e1; e += 256) atomicAdd(&cnt[staging[e] >> 25], 1);
  __syncthreads();
  if (t < 128 && node0 + t < N)
    dinv[node0 + t] = rsqrtf((float)(cnt[t] + 1));  // +1 = self loop
}

// ---------------- Weight-chain stage: C(128x16) = W(128x128) @ B(128x{10|16}) ----

__global__ __launch_bounds__(256) void k_stage(const float* __restrict__ W,
                                               const float* __restrict__ Bsrc, int bcols,
                                               const float* __restrict__ bias,
                                               float* __restrict__ cvec_out,
                                               float* __restrict__ Cout) {
  __shared__ float Ws[16][129];
  __shared__ float Bs[128][17];
  int t = threadIdx.x;
  int r0 = blockIdx.x * 16;
  for (int i = t; i < 2048; i += 256) {
    int k = i >> 4, o = i & 15;
    Bs[k][o] = (o < bcols) ? Bsrc[k * bcols + o] : 0.f;
  }
  for (int i = t; i < 2048; i += 256) {
    int r = i >> 7, c = i & 127;
    Ws[r][c] = W[(size_t)(r0 + r) * 128 + c];
  }
  __syncthreads();
  if (blockIdx.x == 0 && t < 16) {
    float a = 0.f;
    for (int k = 0; k < 128; k++) a += bias[k] * Bs[k][t];
    cvec_out[t] = a;
  }
  int row = t >> 4, o = t & 15;
  float acc = 0.f;
#pragma unroll 8
  for (int k = 0; k < 128; k++) acc += Ws[row][k] * Bs[k][o];
  Cout[(size_t)(r0 + row) * 16 + o] = acc;
}

// ---------------- S0 = dinv * (X @ Y16): LDS-tiled skinny GEMM ----------------
// 128 nodes/block, 256 threads. Thread microtile: 4 nodes x 2 cols.

__global__ __launch_bounds__(256) void k_xy(const float* __restrict__ X,
                                            const float* __restrict__ Y16,
                                            const float* __restrict__ dinv,
                                            float* __restrict__ S, int N) {
  __shared__ float Xs[128][132];
  __shared__ float Yt[16][132];  // Yt[o][k]
  int t = threadIdx.x;
  int n0 = blockIdx.x * 128;
  for (int i = t; i < 2048; i += 256) {
    int k = i >> 4, o = i & 15;
    Yt[o][k] = Y16[k * 16 + o];
  }
#pragma unroll
  for (int it = 0; it < 16; it++) {
    int idx = t + it * 256;
    int r = idx >> 5;
    int c4 = idx & 31;
    int row = n0 + r;
    float4 v = *(const float4*)&X[(size_t)(row < N ? row : 0) * 128 + c4 * 4];
    *(float4*)&Xs[r][c4 * 4] = v;
  }
  __syncthreads();
  int cp = t & 7;                  // col pair: cols 2cp, 2cp+1
  int q = t >> 3;                  // nodes q, q+32, q+64, q+96
  float acc[4][2];
#pragma unroll
  for (int i = 0; i < 4; i++) { acc[i][0] = 0.f; acc[i][1] = 0.f; }
  const float4* y0r = (const float4*)&Yt[2 * cp][0];
  const float4* y1r = (const float4*)&Yt[2 * cp + 1][0];
#pragma unroll 4
  for (int k4 = 0; k4 < 32; k4++) {
    float4 y0 = y0r[k4];
    float4 y1 = y1r[k4];
#pragma unroll
    for (int i = 0; i < 4; i++) {
      float4 xv = *(const float4*)&Xs[q + 32 * i][k4 * 4];
      acc[i][0] += xv.x * y0.x + xv.y * y0.y + xv.z * y0.z + xv.w * y0.w;
      acc[i][1] += xv.x * y1.x + xv.y * y1.y + xv.z * y1.z + xv.w * y1.w;
    }
  }
#pragma unroll
  for (int i = 0; i < 4; i++) {
    int node = n0 + q + 32 * i;
    if (node < N) {
      float di = dinv[node];
      *(float2*)&S[(size_t)node * 16 + 2 * cp] =
          make_float2(acc[i][0] * di, acc[i][1] * di);
    }
  }
}

// ---------------- Push aggregation from bucketed staging ----------------
// One block per 128-node bucket. Edge-parallel: each thread streams edges,
// gathers S[src] cols 0..9 and accumulates into LDS acc (stride 13 ->
// bank-decorrelated, ~2-way conflicts = free). Epilogue adds self + scales.
// g = (A+I).S; out = last ? dinv*g + c : dinv^2*g + dinv*c

__global__ __launch_bounds__(256) void k_aggp(const float* __restrict__ Sin,
                                              const unsigned* __restrict__ staging,
                                              const int* __restrict__ bbase,
                                              const float* __restrict__ dinv,
                                              const float* __restrict__ cvec,
                                              float* __restrict__ Sout,
                                              int N, int last) {
  __shared__ float acc[128 * 13];
  int t = threadIdx.x, k = blockIdx.x;
  int node0 = k << BK_SHIFT;
  for (int i = t; i < 128 * 13; i += 256) acc[i] = 0.f;
  __syncthreads();
  int e0 = bbase[k], e1 = bbase[k + 1];
  int e = e0 + t;
  // 2-unrolled edge stream (breaks the staging->gather dependency chain)
  for (; e + 256 < e1; e += 512) {
    unsigned p0 = staging[e];
    unsigned p1 = staging[e + 256];
    const float* r0 = &Sin[(size_t)(p0 & 0x01FFFFFFu) * 16];
    const float* r1 = &Sin[(size_t)(p1 & 0x01FFFFFFu) * 16];
    float4 a0 = *(const float4*)r0;
    float4 b0 = *(const float4*)(r0 + 4);
    float2 c0 = *(const float2*)(r0 + 8);
    float4 a1 = *(const float4*)r1;
    float4 b1 = *(const float4*)(r1 + 4);
    float2 c1 = *(const float2*)(r1 + 8);
    float* q0 = &acc[(p0 >> 25) * 13];
    float* q1 = &acc[(p1 >> 25) * 13];
    atomicAdd(q0 + 0, a0.x); atomicAdd(q0 + 1, a0.y);
    atomicAdd(q0 + 2, a0.z); atomicAdd(q0 + 3, a0.w);
    atomicAdd(q0 + 4, b0.x); atomicAdd(q0 + 5, b0.y);
    atomicAdd(q0 + 6, b0.z); atomicAdd(q0 + 7, b0.w);
    atomicAdd(q0 + 8, c0.x); atomicAdd(q0 + 9, c0.y);
    atomicAdd(q1 + 0, a1.x); atomicAdd(q1 + 1, a1.y);
    atomicAdd(q1 + 2, a1.z); atomicAdd(q1 + 3, a1.w);
    atomicAdd(q1 + 4, b1.x); atomicAdd(q1 + 5, b1.y);
    atomicAdd(q1 + 6, b1.z); atomicAdd(q1 + 7, b1.w);
    atomicAdd(q1 + 8, c1.x); atomicAdd(q1 + 9, c1.y);
  }
  if (e < e1) {
    unsigned p0 = staging[e];
    const float* r0 = &Sin[(size_t)(p0 & 0x01FFFFFFu) * 16];
    float4 a0 = *(const float4*)r0;
    float4 b0 = *(const float4*)(r0 + 4);
    float2 c0 = *(const float2*)(r0 + 8);
    float* q0 = &acc[(p0 >> 25) * 13];
    atomicAdd(q0 + 0, a0.x); atomicAdd(q0 + 1, a0.y);
    atomicAdd(q0 + 2, a0.z); atomicAdd(q0 + 3, a0.w);
    atomicAdd(q0 + 4, b0.x); atomicAdd(q0 + 5, b0.y);
    atomicAdd(q0 + 6, b0.z); atomicAdd(q0 + 7, b0.w);
    atomicAdd(q0 + 8, c0.x); atomicAdd(q0 + 9, c0.y);
  }
  __syncthreads();
  // epilogue: 2 lanes per node
  int d = t >> 1, o = t & 1;
  int node = node0 + d;
  if (node >= N) return;
  float di = dinv[node];
  float sg = last ? di : di * di;
  float sc = last ? 1.f : di;
  const float* a = &acc[d * 13];
  if (o == 0) {
    float4 s4 = *(const float4*)&Sin[(size_t)node * 16];
    float2 s2 = *(const float2*)&Sin[(size_t)node * 16 + 8];
    float4 out;
    out.x = sg * (a[0] + s4.x) + sc * cvec[0];
    out.y = sg * (a[1] + s4.y) + sc * cvec[1];
    out.z = sg * (a[2] + s4.z) + sc * cvec[2];
    out.w = sg * (a[3] + s4.w) + sc * cvec[3];
    *(float4*)&Sout[(size_t)node * 16] = out;
    float2 o2;
    o2.x = sg * (a[8] + s2.x) + sc * cvec[8];
    o2.y = sg * (a[9] + s2.y) + sc * cvec[9];
    *(float2*)&Sout[(size_t)node * 16 + 8] = o2;
  } else {
    float4 s4 = *(const float4*)&Sin[(size_t)node * 16 + 4];
    float4 out;
    out.x = sg * (a[4] + s4.x) + sc * cvec[4];
    out.y = sg * (a[5] + s4.y) + sc * cvec[5];
    out.z = sg * (a[6] + s4.z) + sc * cvec[6];
    out.w = sg * (a[7] + s4.w) + sc * cvec[7];
    *(float4*)&Sout[(size_t)node * 16 + 4] = out;
  }
}

// ---------------- Pooling + bias (gbounds inlined) ----------------

__global__ __launch_bounds__(128) void k_pool(const float* __restrict__ Z,
                                              const int* __restrict__ batch,
                                              const float* __restrict__ b_out,
                                              float* __restrict__ out, int N, int G) {
  __shared__ float red[8][16];
  __shared__ int bounds[2];
  int g = blockIdx.x;
  int t = threadIdx.x;
  if (t < 2) {
    int target = g + t;
    int lo = 0, hi = N;
    while (lo < hi) {
      int mid = (lo + hi) >> 1;
      if (batch[mid] < target) lo = mid + 1; else hi = mid;
    }
    bounds[t] = lo;
  }
  __syncthreads();
  int s = bounds[0], e = bounds[1];
  int f = t & 15, c = t >> 4;
  float acc = 0.f;
  if (f < 10) {
    for (int n = s + c; n < e; n += 8) acc += Z[(size_t)n * 16 + f];
  }
  red[c][f] = acc;
  __syncthreads();
  if (c == 0 && f < 10) {
    float a = 0.f;
#pragma unroll
    for (int i = 0; i < 8; i++) a += red[i][f];
    out[g * 10 + f] = a / fmaxf((float)(e - s), 1.f) + b_out[f];
  }
}

// ---------------- launch ----------------

extern "C" void kernel_launch(void* const* d_in, const int* in_sizes, int n_in,
                              void* d_out, int out_size, void* d_ws, size_t ws_size,
                              hipStream_t stream) {
  const float* x     = (const float*)d_in[0];
  const int*   eidx  = (const int*)d_in[1];
  const int*   batch = (const int*)d_in[2];
  const float* W_in  = (const float*)d_in[3];
  const float* b_in  = (const float*)d_in[4];
  const float* W_hid = (const float*)d_in[5];
  const float* b_hid = (const float*)d_in[6];
  const float* W_out = (const float*)d_in[7];
  const float* b_out = (const float*)d_in[8];

  const int N = in_sizes[0] / 128;
  const int E = in_sizes[1] / 2;
  const int G = out_size / 10;

  const int* src = eidx;
  const int* dst = eidx + E;

  const int NB = (N + 127) >> BK_SHIFT;
  const int NBLK = (E + CHUNK - 1) / CHUNK;

  char* ws = (char*)d_ws;
  size_t off = 0;
  auto alloc = [&](size_t b) {
    char* p = ws + off;
    off = (off + b + 255) & ~(size_t)255;
    return p;
  };
  unsigned* staging = (unsigned*)alloc((size_t)E * 4);
  int*   blkcnt  = (int*)alloc((size_t)NB * NBLK * 4);
  int*   btot    = (int*)alloc((size_t)NB * 4);
  int*   bbase   = (int*)alloc((size_t)(NB + 1) * 4);
  float* dinv    = (float*)alloc((size_t)N * 4);
  float* stateA  = (float*)alloc((size_t)N * 16 * 4);
  float* stateB  = (float*)alloc((size_t)N * 16 * 4);
  float* ppA     = (float*)alloc(128 * 16 * 4);
  float* ppB     = (float*)alloc(128 * 16 * 4);
  float* Y16     = (float*)alloc(128 * 16 * 4);
  float* cvec    = (float*)alloc(4 * 16 * 4);
  (void)ws_size; (void)n_in;

  // Weight chain as 4 small GEMM stages (each emits its chain-bias term)
  k_stage<<<8, 256, 0, stream>>>(W_hid + 2 * 16384, W_out, 10, b_hid + 2 * 128, cvec + 48, ppA);
  k_stage<<<8, 256, 0, stream>>>(W_hid + 1 * 16384, ppA, 16, b_hid + 1 * 128, cvec + 32, ppB);
  k_stage<<<8, 256, 0, stream>>>(W_hid + 0 * 16384, ppB, 16, b_hid + 0 * 128, cvec + 16, ppA);
  k_stage<<<8, 256, 0, stream>>>(W_in, ppA, 16, b_in, cvec + 0, Y16);

  // Bucketed edge staging (no global atomics, no fences, no col build)
  k_bucket_count<<<NBLK, 256, 0, stream>>>(dst, blkcnt, E, NB, NBLK);
  k_bucket_scanB<<<NB, 256, 0, stream>>>(blkcnt, btot, NBLK);
  k_bucket_base<<<1, 1024, 0, stream>>>(btot, bbase, NB);
  k_bucket_scatter<<<NBLK, 256, 0, stream>>>(src, dst, blkcnt, bbase, staging, E, NB, NBLK);
  k_deg<<<NB, 256, 0, stream>>>(staging, bbase, dinv, N);

  // S0 = dinv * (X @ Y)
  k_xy<<<(N + 127) / 128, 256, 0, stream>>>(x, Y16, dinv, stateA, N);

  // 4 push-aggregation passes straight from staging
  float* zi = stateA;
  float* zo = stateB;
  for (int l = 0; l < 4; l++) {
    k_aggp<<<NB, 256, 0, stream>>>(zi, staging, bbase, dinv, cvec + 16 * l, zo, N,
                                   (l == 3) ? 1 : 0);
    float* t = zi; zi = zo; zo = t;
  }

  k_pool<<<G, 128, 0, stream>>>(zi, batch, b_out, (float*)d_out, N, G);
}

// Round 11
// 313.973 us; speedup vs baseline: 1.9942x; 1.9942x over previous
//
#include <hip/hip_runtime.h>

#define BK_SHIFT 7
#define NB_MAX 1024
#define CHUNK 8192

typedef float f4u __attribute__((ext_vector_type(4), aligned(4)));

// ---------------- Bucketed CSR build (no global atomics) ----------------

__global__ __launch_bounds__(256) void k_bucket_count(const int* __restrict__ dst,
                                                      int* __restrict__ blkcnt,
                                                      int E, int NB, int NBLK) {
  __shared__ int cnt[NB_MAX];
  int t = threadIdx.x, b = blockIdx.x;
  for (int i = t; i < NB; i += 256) cnt[i] = 0;
  __syncthreads();
  int e0 = b * CHUNK, e1 = min(E, e0 + CHUNK);
  if (e1 - e0 == CHUNK) {
    const int4* d4 = (const int4*)(dst + e0);
#pragma unroll 2
    for (int i = t; i < CHUNK / 4; i += 256) {
      int4 v = d4[i];
      atomicAdd(&cnt[v.x >> BK_SHIFT], 1);
      atomicAdd(&cnt[v.y >> BK_SHIFT], 1);
      atomicAdd(&cnt[v.z >> BK_SHIFT], 1);
      atomicAdd(&cnt[v.w >> BK_SHIFT], 1);
    }
  } else {
    for (int e = e0 + t; e < e1; e += 256) atomicAdd(&cnt[dst[e] >> BK_SHIFT], 1);
  }
  __syncthreads();
  for (int i = t; i < NB; i += 256) blkcnt[(size_t)i * NBLK + b] = cnt[i];
}

__global__ __launch_bounds__(256) void k_bucket_scanB(int* __restrict__ blkcnt,
                                                      int* __restrict__ btot, int NBLK) {
  __shared__ int v[256];
  int t = threadIdx.x, k = blockIdx.x;
  int x = (t < NBLK) ? blkcnt[(size_t)k * NBLK + t] : 0;
  v[t] = x;
  __syncthreads();
  for (int off = 1; off < 256; off <<= 1) {
    int u = (t >= off) ? v[t - off] : 0;
    __syncthreads();
    v[t] += u;
    __syncthreads();
  }
  if (t < NBLK) blkcnt[(size_t)k * NBLK + t] = v[t] - x;  // exclusive
  if (t == 255) btot[k] = v[255];
}

__global__ __launch_bounds__(1024) void k_bucket_base(const int* __restrict__ btot,
                                                      int* __restrict__ bbase, int NB) {
  __shared__ int v[1024];
  int t = threadIdx.x;
  int x = (t < NB) ? btot[t] : 0;
  v[t] = x;
  __syncthreads();
  for (int off = 1; off < 1024; off <<= 1) {
    int u = (t >= off) ? v[t - off] : 0;
    __syncthreads();
    v[t] += u;
    __syncthreads();
  }
  if (t < NB) bbase[t] = v[t] - x;
  if (t == 1023) bbase[NB] = v[1023];
}

__global__ __launch_bounds__(256) void k_bucket_scatter(const int* __restrict__ src,
                                                        const int* __restrict__ dst,
                                                        const int* __restrict__ blkoff,
                                                        const int* __restrict__ bbase,
                                                        unsigned* __restrict__ staging,
                                                        int E, int NB, int NBLK) {
  __shared__ int curs[NB_MAX];
  int t = threadIdx.x, b = blockIdx.x;
  for (int i = t; i < NB; i += 256) curs[i] = bbase[i] + blkoff[(size_t)i * NBLK + b];
  __syncthreads();
  int e0 = b * CHUNK, e1 = min(E, e0 + CHUNK);
  for (int e = e0 + t; e < e1; e += 256) {
    int d = dst[e], s = src[e];
    int slot = atomicAdd(&curs[d >> BK_SHIFT], 1);
    staging[slot] = ((unsigned)(d & 127) << 25) | (unsigned)s;
  }
}

__global__ __launch_bounds__(256) void k_csr_build(const unsigned* __restrict__ staging,
                                                   const int* __restrict__ bbase,
                                                   int* __restrict__ roff,
                                                   float* __restrict__ dinv,
                                                   int* __restrict__ col,
                                                   int N, int NB, int E) {
  __shared__ int cnt[128];
  __shared__ int sa[128], sb[128];
  __shared__ int cursor[128];
  int t = threadIdx.x, k = blockIdx.x;
  int node0 = k << BK_SHIFT;
  int nNodes = min(128, N - node0);
  int e0 = bbase[k], e1 = bbase[k + 1];
  if (t < 128) cnt[t] = 0;
  __syncthreads();
  for (int e = e0 + t; e < e1; e += 256) atomicAdd(&cnt[staging[e] >> 25], 1);
  __syncthreads();
  int* a = sa;
  int* bq = sb;
  if (t < 128) a[t] = cnt[t];
  __syncthreads();
  for (int off = 1; off < 128; off <<= 1) {
    if (t < 128) bq[t] = (t >= off) ? a[t] + a[t - off] : a[t];
    __syncthreads();
    int* tmp = a; a = bq; bq = tmp;
  }
  if (t < 128) {
    int excl = e0 + ((t > 0) ? a[t - 1] : 0);
    cursor[t] = excl;
    if (t < nNodes) {
      roff[node0 + t] = excl;
      dinv[node0 + t] = rsqrtf((float)(cnt[t] + 1));  // +1 = self loop
    }
  }
  if (k == NB - 1 && t == 0) roff[N] = E;
  __syncthreads();
  for (int e = e0 + t; e < e1; e += 256) {
    unsigned p = staging[e];
    int slot = atomicAdd(&cursor[p >> 25], 1);
    col[slot] = (int)(p & 0x01FFFFFFu);
  }
}

// ---------------- Weight-chain stage: C(128x16) = W(128x128) @ B(128x{10|16}) ----

__global__ __launch_bounds__(256) void k_stage(const float* __restrict__ W,
                                               const float* __restrict__ Bsrc, int bcols,
                                               const float* __restrict__ bias,
                                               float* __restrict__ cvec_out,
                                               float* __restrict__ Cout) {
  __shared__ float Ws[16][129];
  __shared__ float Bs[128][17];
  int t = threadIdx.x;
  int r0 = blockIdx.x * 16;
  for (int i = t; i < 2048; i += 256) {
    int k = i >> 4, o = i & 15;
    Bs[k][o] = (o < bcols) ? Bsrc[k * bcols + o] : 0.f;
  }
  for (int i = t; i < 2048; i += 256) {
    int r = i >> 7, c = i & 127;
    Ws[r][c] = W[(size_t)(r0 + r) * 128 + c];
  }
  __syncthreads();
  if (blockIdx.x == 0 && t < 16) {
    float a = 0.f;
    for (int k = 0; k < 128; k++) a += bias[k] * Bs[k][t];
    cvec_out[t] = a;
  }
  int row = t >> 4, o = t & 15;
  float acc = 0.f;
#pragma unroll 8
  for (int k = 0; k < 128; k++) acc += Ws[row][k] * Bs[k][o];
  Cout[(size_t)(r0 + row) * 16 + o] = acc;
}

// ---------------- S0 = dinv * (X @ Y16): LDS-tiled skinny GEMM, packed 10-wide out ----

__global__ __launch_bounds__(256) void k_xy(const float* __restrict__ X,
                                            const float* __restrict__ Y16,
                                            const float* __restrict__ dinv,
                                            float* __restrict__ S, int N) {
  __shared__ float Xs[128][132];
  __shared__ float Yt[16][132];  // Yt[o][k]
  int t = threadIdx.x;
  int n0 = blockIdx.x * 128;
  for (int i = t; i < 2048; i += 256) {
    int k = i >> 4, o = i & 15;
    Yt[o][k] = Y16[k * 16 + o];
  }
#pragma unroll
  for (int it = 0; it < 16; it++) {
    int idx = t + it * 256;
    int r = idx >> 5;
    int c4 = idx & 31;
    int row = n0 + r;
    float4 v = *(const float4*)&X[(size_t)(row < N ? row : 0) * 128 + c4 * 4];
    *(float4*)&Xs[r][c4 * 4] = v;
  }
  __syncthreads();
  int cp = t & 7;                  // col pair: cols 2cp, 2cp+1 (cp<=4 real)
  int q = t >> 3;                  // nodes q, q+32, q+64, q+96
  float acc[4][2];
#pragma unroll
  for (int i = 0; i < 4; i++) { acc[i][0] = 0.f; acc[i][1] = 0.f; }
  const float4* y0r = (const float4*)&Yt[2 * cp][0];
  const float4* y1r = (const float4*)&Yt[2 * cp + 1][0];
#pragma unroll 4
  for (int k4 = 0; k4 < 32; k4++) {
    float4 y0 = y0r[k4];
    float4 y1 = y1r[k4];
#pragma unroll
    for (int i = 0; i < 4; i++) {
      float4 xv = *(const float4*)&Xs[q + 32 * i][k4 * 4];
      acc[i][0] += xv.x * y0.x + xv.y * y0.y + xv.z * y0.z + xv.w * y0.w;
      acc[i][1] += xv.x * y1.x + xv.y * y1.y + xv.z * y1.z + xv.w * y1.w;
    }
  }
  if (cp > 4) return;
#pragma unroll
  for (int i = 0; i < 4; i++) {
    int node = n0 + q + 32 * i;
    if (node < N) {
      float di = dinv[node];
      S[(size_t)node * 10 + 2 * cp]     = acc[i][0] * di;
      S[(size_t)node * 10 + 2 * cp + 1] = acc[i][1] * di;
    }
  }
}

// ---------------- Pull aggregation on packed 40-B rows (table = 4.0 MB ~ L2) ----
// 2 lanes/node, convergent: lane o loads f4 at +16o B (cols 4o..4o+3) + scalar
// col 8+o. col stream non-temporal; Sout stores non-temporal (protect L2 table).
// g = (A+I).S; out = last ? dinv*g + c : dinv^2*g + dinv*c

__global__ __launch_bounds__(256) void k_agg(const float* __restrict__ Sin,
                                             const int* __restrict__ col,
                                             const int* __restrict__ roff,
                                             const float* __restrict__ dinv,
                                             const float* __restrict__ cvec,
                                             float* __restrict__ Sout, int N, int last) {
  int node = blockIdx.x * 128 + (threadIdx.x >> 1);
  int o = threadIdx.x & 1;
  if (node >= N) return;
  const float* sb = Sin + (size_t)node * 10;
  f4u z = *(const f4u*)(sb + 4 * o);
  float a0 = z.x, a1 = z.y, a2 = z.z, a3 = z.w;
  float ar = sb[8 + o];
  int j = roff[node], e = roff[node + 1];
  for (; j + 3 < e; j += 4) {
    int s0 = __builtin_nontemporal_load(col + j);
    int s1 = __builtin_nontemporal_load(col + j + 1);
    int s2 = __builtin_nontemporal_load(col + j + 2);
    int s3 = __builtin_nontemporal_load(col + j + 3);
    const float* b0 = Sin + (size_t)s0 * 10;
    const float* b1 = Sin + (size_t)s1 * 10;
    const float* b2 = Sin + (size_t)s2 * 10;
    const float* b3 = Sin + (size_t)s3 * 10;
    f4u v0 = *(const f4u*)(b0 + 4 * o);
    f4u v1 = *(const f4u*)(b1 + 4 * o);
    f4u v2 = *(const f4u*)(b2 + 4 * o);
    f4u v3 = *(const f4u*)(b3 + 4 * o);
    float w0 = b0[8 + o], w1 = b1[8 + o], w2 = b2[8 + o], w3 = b3[8 + o];
    a0 += v0.x + v1.x + v2.x + v3.x;
    a1 += v0.y + v1.y + v2.y + v3.y;
    a2 += v0.z + v1.z + v2.z + v3.z;
    a3 += v0.w + v1.w + v2.w + v3.w;
    ar += w0 + w1 + w2 + w3;
  }
  for (; j < e; j++) {
    int s0 = __builtin_nontemporal_load(col + j);
    const float* b0 = Sin + (size_t)s0 * 10;
    f4u v0 = *(const f4u*)(b0 + 4 * o);
    a0 += v0.x; a1 += v0.y; a2 += v0.z; a3 += v0.w;
    ar += b0[8 + o];
  }
  float di = dinv[node];
  float sg = last ? di : di * di;
  float sc = last ? 1.f : di;
  const float* cv = cvec + 4 * o;
  float* op = Sout + (size_t)node * 10 + 4 * o;
  __builtin_nontemporal_store(sg * a0 + sc * cv[0], op + 0);
  __builtin_nontemporal_store(sg * a1 + sc * cv[1], op + 1);
  __builtin_nontemporal_store(sg * a2 + sc * cv[2], op + 2);
  __builtin_nontemporal_store(sg * a3 + sc * cv[3], op + 3);
  __builtin_nontemporal_store(sg * ar + sc * cvec[8 + o],
                              Sout + (size_t)node * 10 + 8 + o);
}

// ---------------- Pooling + bias (gbounds inlined), packed rows ----------------

__global__ __launch_bounds__(128) void k_pool(const float* __restrict__ Z,
                                              const int* __restrict__ batch,
                                              const float* __restrict__ b_out,
                                              float* __restrict__ out, int N, int G) {
  __shared__ float red[8][16];
  __shared__ int bounds[2];
  int g = blockIdx.x;
  int t = threadIdx.x;
  if (t < 2) {
    int target = g + t;
    int lo = 0, hi = N;
    while (lo < hi) {
      int mid = (lo + hi) >> 1;
      if (batch[mid] < target) lo = mid + 1; else hi = mid;
    }
    bounds[t] = lo;
  }
  __syncthreads();
  int s = bounds[0], e = bounds[1];
  int f = t & 15, c = t >> 4;
  float acc = 0.f;
  if (f < 10) {
    for (int n = s + c; n < e; n += 8) acc += Z[(size_t)n * 10 + f];
  }
  red[c][f] = acc;
  __syncthreads();
  if (c == 0 && f < 10) {
    float a = 0.f;
#pragma unroll
    for (int i = 0; i < 8; i++) a += red[i][f];
    out[g * 10 + f] = a / fmaxf((float)(e - s), 1.f) + b_out[f];
  }
}

// ---------------- launch ----------------

extern "C" void kernel_launch(void* const* d_in, const int* in_sizes, int n_in,
                              void* d_out, int out_size, void* d_ws, size_t ws_size,
                              hipStream_t stream) {
  const float* x     = (const float*)d_in[0];
  const int*   eidx  = (const int*)d_in[1];
  const int*   batch = (const int*)d_in[2];
  const float* W_in  = (const float*)d_in[3];
  const float* b_in  = (const float*)d_in[4];
  const float* W_hid = (const float*)d_in[5];
  const float* b_hid = (const float*)d_in[6];
  const float* W_out = (const float*)d_in[7];
  const float* b_out = (const float*)d_in[8];

  const int N = in_sizes[0] / 128;
  const int E = in_sizes[1] / 2;
  const int G = out_size / 10;

  const int* src = eidx;
  const int* dst = eidx + E;

  const int NB = (N + 127) >> BK_SHIFT;
  const int NBLK = (E + CHUNK - 1) / CHUNK;

  char* ws = (char*)d_ws;
  size_t off = 0;
  auto alloc = [&](size_t b) {
    char* p = ws + off;
    off = (off + b + 255) & ~(size_t)255;
    return p;
  };
  unsigned* staging = (unsigned*)alloc((size_t)E * 4);
  int*   col     = (int*)alloc((size_t)E * 4);
  int*   blkcnt  = (int*)alloc((size_t)NB * NBLK * 4);
  int*   btot    = (int*)alloc((size_t)NB * 4);
  int*   bbase   = (int*)alloc((size_t)(NB + 1) * 4);
  int*   roff    = (int*)alloc((size_t)(N + 1) * 4);
  float* dinv    = (float*)alloc((size_t)N * 4);
  float* stateA  = (float*)alloc((size_t)N * 10 * 4 + 16);
  float* stateB  = (float*)alloc((size_t)N * 10 * 4 + 16);
  float* ppA     = (float*)alloc(128 * 16 * 4);
  float* ppB     = (float*)alloc(128 * 16 * 4);
  float* Y16     = (float*)alloc(128 * 16 * 4);
  float* cvec    = (float*)alloc(4 * 16 * 4);
  (void)ws_size; (void)n_in;

  // Weight chain as 4 small GEMM stages (each emits its chain-bias term)
  k_stage<<<8, 256, 0, stream>>>(W_hid + 2 * 16384, W_out, 10, b_hid + 2 * 128, cvec + 48, ppA);
  k_stage<<<8, 256, 0, stream>>>(W_hid + 1 * 16384, ppA, 16, b_hid + 1 * 128, cvec + 32, ppB);
  k_stage<<<8, 256, 0, stream>>>(W_hid + 0 * 16384, ppB, 16, b_hid + 0 * 128, cvec + 16, ppA);
  k_stage<<<8, 256, 0, stream>>>(W_in, ppA, 16, b_in, cvec + 0, Y16);

  // Bucketed CSR build (no global atomics, no fences)
  k_bucket_count<<<NBLK, 256, 0, stream>>>(dst, blkcnt, E, NB, NBLK);
  k_bucket_scanB<<<NB, 256, 0, stream>>>(blkcnt, btot, NBLK);
  k_bucket_base<<<1, 1024, 0, stream>>>(btot, bbase, NB);
  k_bucket_scatter<<<NBLK, 256, 0, stream>>>(src, dst, blkcnt, bbase, staging, E, NB, NBLK);
  k_csr_build<<<NB, 256, 0, stream>>>(staging, bbase, roff, dinv, col, N, NB, E);

  // S0 = dinv * (X @ Y), packed 10-wide
  k_xy<<<(N + 127) / 128, 256, 0, stream>>>(x, Y16, dinv, stateA, N);

  // 4 pull passes on the packed (L2-resident) table
  float* zi = stateA;
  float* zo = stateB;
  for (int l = 0; l < 4; l++) {
    k_agg<<<(N + 127) / 128, 256, 0, stream>>>(zi, col, roff, dinv,
                                               cvec + 16 * l, zo, N, (l == 3) ? 1 : 0);
    float* t = zi; zi = zo; zo = t;
  }

  k_pool<<<G, 128, 0, stream>>>(zi, batch, b_out, (float*)d_out, N, G);
}

// Round 12
// 286.551 us; speedup vs baseline: 2.1850x; 1.0957x over previous
//
#include <hip/hip_runtime.h>

#define BK_SHIFT 7
#define NB_MAX 1024
#define CHUNK 8192

// ---------------- Bucketed CSR build (no global atomics) ----------------

// Pass A: per-block bucket histogram (bucket = dst >> 7), int4-vectorized.
__global__ __launch_bounds__(256) void k_bucket_count(const int* __restrict__ dst,
                                                      int* __restrict__ blkcnt,
                                                      int E, int NB, int NBLK) {
  __shared__ int cnt[NB_MAX];
  int t = threadIdx.x, b = blockIdx.x;
  for (int i = t; i < NB; i += 256) cnt[i] = 0;
  __syncthreads();
  int e0 = b * CHUNK, e1 = min(E, e0 + CHUNK);
  if (e1 - e0 == CHUNK) {
    const int4* d4 = (const int4*)(dst + e0);
#pragma unroll 2
    for (int i = t; i < CHUNK / 4; i += 256) {
      int4 v = d4[i];
      atomicAdd(&cnt[v.x >> BK_SHIFT], 1);
      atomicAdd(&cnt[v.y >> BK_SHIFT], 1);
      atomicAdd(&cnt[v.z >> BK_SHIFT], 1);
      atomicAdd(&cnt[v.w >> BK_SHIFT], 1);
    }
  } else {
    for (int e = e0 + t; e < e1; e += 256) atomicAdd(&cnt[dst[e] >> BK_SHIFT], 1);
  }
  __syncthreads();
  for (int i = t; i < NB; i += 256) blkcnt[(size_t)i * NBLK + b] = cnt[i];
}

// Pass B: per-bucket exclusive scan across blocks (in place), bucket totals out.
__global__ __launch_bounds__(256) void k_bucket_scanB(int* __restrict__ blkcnt,
                                                      int* __restrict__ btot, int NBLK) {
  __shared__ int v[256];
  int t = threadIdx.x, k = blockIdx.x;
  int x = (t < NBLK) ? blkcnt[(size_t)k * NBLK + t] : 0;
  v[t] = x;
  __syncthreads();
  for (int off = 1; off < 256; off <<= 1) {
    int u = (t >= off) ? v[t - off] : 0;
    __syncthreads();
    v[t] += u;
    __syncthreads();
  }
  if (t < NBLK) blkcnt[(size_t)k * NBLK + t] = v[t] - x;  // exclusive
  if (t == 255) btot[k] = v[255];
}

// Pass B2: exclusive scan over bucket totals -> bucket base offsets
__global__ __launch_bounds__(1024) void k_bucket_base(const int* __restrict__ btot,
                                                      int* __restrict__ bbase, int NB) {
  __shared__ int v[1024];
  int t = threadIdx.x;
  int x = (t < NB) ? btot[t] : 0;
  v[t] = x;
  __syncthreads();
  for (int off = 1; off < 1024; off <<= 1) {
    int u = (t >= off) ? v[t - off] : 0;
    __syncthreads();
    v[t] += u;
    __syncthreads();
  }
  if (t < NB) bbase[t] = v[t] - x;
  if (t == 1023) bbase[NB] = v[1023];
}

// Pass C: LDS-sorted scatter. Block sorts its chunk by bucket in LDS, then
// writes out in sorted order -> consecutive lanes hit consecutive addresses
// within each ~42-B run (vs 1 open line per bucket x 782 buckets before).
__global__ __launch_bounds__(256) void k_bucket_scatter(const int* __restrict__ src,
                                                        const int* __restrict__ dst,
                                                        const int* __restrict__ blkoff,
                                                        const int* __restrict__ bbase,
                                                        unsigned* __restrict__ staging,
                                                        int E, int NB, int NBLK) {
  __shared__ unsigned sval[CHUNK];   // 32 KB: packed payloads in bucket-sorted order
  __shared__ int ga0[CHUNK];         // 32 KB: per-slot global address offset
  __shared__ int lcnt[NB_MAX];       // local bucket counts
  __shared__ int gofs[NB_MAX];       // global base - local offset, per bucket
  __shared__ int curs[NB_MAX];       // local cursors
  __shared__ int v[256];
  int t = threadIdx.x, b = blockIdx.x;
  for (int i = t; i < NB; i += 256) lcnt[i] = 0;
  __syncthreads();
  int e0 = b * CHUNK, e1 = min(E, e0 + CHUNK);
  int chunkE = e1 - e0;
  // local histogram
  if (chunkE == CHUNK) {
    const int4* d4 = (const int4*)(dst + e0);
#pragma unroll 2
    for (int i = t; i < CHUNK / 4; i += 256) {
      int4 w = d4[i];
      atomicAdd(&lcnt[w.x >> BK_SHIFT], 1);
      atomicAdd(&lcnt[w.y >> BK_SHIFT], 1);
      atomicAdd(&lcnt[w.z >> BK_SHIFT], 1);
      atomicAdd(&lcnt[w.w >> BK_SHIFT], 1);
    }
  } else {
    for (int e = e0 + t; e < e1; e += 256) atomicAdd(&lcnt[dst[e] >> BK_SHIFT], 1);
  }
  __syncthreads();
  // exclusive scan of lcnt (4 buckets/thread), then per-bucket setup
  int base4 = t * 4;
  int a0 = (base4 + 0 < NB) ? lcnt[base4 + 0] : 0;
  int a1 = (base4 + 1 < NB) ? lcnt[base4 + 1] : 0;
  int a2 = (base4 + 2 < NB) ? lcnt[base4 + 2] : 0;
  int a3 = (base4 + 3 < NB) ? lcnt[base4 + 3] : 0;
  int s = a0 + a1 + a2 + a3;
  v[t] = s;
  __syncthreads();
  for (int off = 1; off < 256; off <<= 1) {
    int u = (t >= off) ? v[t - off] : 0;
    __syncthreads();
    v[t] += u;
    __syncthreads();
  }
  int run = v[t] - s;  // exclusive
  {
    int aa[4] = {a0, a1, a2, a3};
#pragma unroll
    for (int i = 0; i < 4; i++) {
      int bk = base4 + i;
      if (bk < NB) {
        gofs[bk] = bbase[bk] + blkoff[(size_t)bk * NBLK + b] - run;
        curs[bk] = run;
        run += aa[i];
      }
    }
  }
  __syncthreads();
  // place edges into LDS-sorted order
  for (int e = e0 + t; e < e1; e += 256) {
    int d = dst[e];
    int sidx = src[e];
    int bk = d >> BK_SHIFT;
    int slot = atomicAdd(&curs[bk], 1);
    sval[slot] = ((unsigned)(d & 127) << 25) | (unsigned)sidx;
    ga0[slot] = gofs[bk];
  }
  __syncthreads();
  // write out in sorted order (dense runs)
  for (int i = t; i < chunkE; i += 256) staging[ga0[i] + i] = sval[i];
}

// Pass D: per-bucket counts -> dinv + roff (dense), then in-bucket scatter of col
__global__ __launch_bounds__(256) void k_csr_build(const unsigned* __restrict__ staging,
                                                   const int* __restrict__ bbase,
                                                   int* __restrict__ roff,
                                                   float* __restrict__ dinv,
                                                   int* __restrict__ col,
                                                   int N, int NB, int E) {
  __shared__ int cnt[128];
  __shared__ int sa[128], sb[128];
  __shared__ int cursor[128];
  int t = threadIdx.x, k = blockIdx.x;
  int node0 = k << BK_SHIFT;
  int nNodes = min(128, N - node0);
  int e0 = bbase[k], e1 = bbase[k + 1];
  if (t < 128) cnt[t] = 0;
  __syncthreads();
  for (int e = e0 + t; e < e1; e += 256) atomicAdd(&cnt[staging[e] >> 25], 1);
  __syncthreads();
  int* a = sa;
  int* bq = sb;
  if (t < 128) a[t] = cnt[t];
  __syncthreads();
  for (int off = 1; off < 128; off <<= 1) {
    if (t < 128) bq[t] = (t >= off) ? a[t] + a[t - off] : a[t];
    __syncthreads();
    int* tmp = a; a = bq; bq = tmp;
  }
  if (t < 128) {
    int excl = e0 + ((t > 0) ? a[t - 1] : 0);
    cursor[t] = excl;
    if (t < nNodes) {
      roff[node0 + t] = excl;
      dinv[node0 + t] = rsqrtf((float)(cnt[t] + 1));  // +1 = self loop
    }
  }
  if (k == NB - 1 && t == 0) roff[N] = E;
  __syncthreads();
  for (int e = e0 + t; e < e1; e += 256) {
    unsigned p = staging[e];
    int slot = atomicAdd(&cursor[p >> 25], 1);
    col[slot] = (int)(p & 0x01FFFFFFu);
  }
}

// ---------------- Weight-chain stage: C(128x16) = W(128x128) @ B(128x{10|16}) ----

__global__ __launch_bounds__(256) void k_stage(const float* __restrict__ W,
                                               const float* __restrict__ Bsrc, int bcols,
                                               const float* __restrict__ bias,
                                               float* __restrict__ cvec_out,
                                               float* __restrict__ Cout) {
  __shared__ float Ws[16][129];
  __shared__ float Bs[128][17];
  int t = threadIdx.x;
  int r0 = blockIdx.x * 16;
  for (int i = t; i < 2048; i += 256) {
    int k = i >> 4, o = i & 15;
    Bs[k][o] = (o < bcols) ? Bsrc[k * bcols + o] : 0.f;
  }
  for (int i = t; i < 2048; i += 256) {
    int r = i >> 7, c = i & 127;
    Ws[r][c] = W[(size_t)(r0 + r) * 128 + c];
  }
  __syncthreads();
  if (blockIdx.x == 0 && t < 16) {
    float a = 0.f;
    for (int k = 0; k < 128; k++) a += bias[k] * Bs[k][t];
    cvec_out[t] = a;
  }
  int row = t >> 4, o = t & 15;
  float acc = 0.f;
#pragma unroll 8
  for (int k = 0; k < 128; k++) acc += Ws[row][k] * Bs[k][o];
  Cout[(size_t)(r0 + row) * 16 + o] = acc;
}

// ---------------- S0 = dinv * (X @ Y16): LDS-tiled skinny GEMM ----------------
// 128 nodes/block, 256 threads. Thread microtile: 4 nodes x 2 cols.

__global__ __launch_bounds__(256) void k_xy(const float* __restrict__ X,
                                            const float* __restrict__ Y16,
                                            const float* __restrict__ dinv,
                                            float* __restrict__ S, int N) {
  __shared__ float Xs[128][132];
  __shared__ float Yt[16][132];  // Yt[o][k]
  int t = threadIdx.x;
  int n0 = blockIdx.x * 128;
  for (int i = t; i < 2048; i += 256) {
    int k = i >> 4, o = i & 15;
    Yt[o][k] = Y16[k * 16 + o];
  }
#pragma unroll
  for (int it = 0; it < 16; it++) {
    int idx = t + it * 256;
    int r = idx >> 5;
    int c4 = idx & 31;
    int row = n0 + r;
    float4 v = *(const float4*)&X[(size_t)(row < N ? row : 0) * 128 + c4 * 4];
    *(float4*)&Xs[r][c4 * 4] = v;
  }
  __syncthreads();
  int cp = t & 7;                  // col pair: cols 2cp, 2cp+1
  int q = t >> 3;                  // nodes q, q+32, q+64, q+96
  float acc[4][2];
#pragma unroll
  for (int i = 0; i < 4; i++) { acc[i][0] = 0.f; acc[i][1] = 0.f; }
  const float4* y0r = (const float4*)&Yt[2 * cp][0];
  const float4* y1r = (const float4*)&Yt[2 * cp + 1][0];
#pragma unroll 4
  for (int k4 = 0; k4 < 32; k4++) {
    float4 y0 = y0r[k4];
    float4 y1 = y1r[k4];
#pragma unroll
    for (int i = 0; i < 4; i++) {
      float4 xv = *(const float4*)&Xs[q + 32 * i][k4 * 4];
      acc[i][0] += xv.x * y0.x + xv.y * y0.y + xv.z * y0.z + xv.w * y0.w;
      acc[i][1] += xv.x * y1.x + xv.y * y1.y + xv.z * y1.z + xv.w * y1.w;
    }
  }
#pragma unroll
  for (int i = 0; i < 4; i++) {
    int node = n0 + q + 32 * i;
    if (node < N) {
      float di = dinv[node];
      *(float2*)&S[(size_t)node * 16 + 2 * cp] =
          make_float2(acc[i][0] * di, acc[i][1] * di);
    }
  }
}

// ---------------- Aggregation on scaled state (16-wide, 4 lanes/node) ----------------
// g = (A+I).S (unweighted gather); out = last ? dinv*g + c : dinv^2*g + dinv*c

__global__ __launch_bounds__(256) void k_agg10(const float4* __restrict__ Sin4,
                                               const int* __restrict__ col,
                                               const int* __restrict__ roff,
                                               const float* __restrict__ dinv,
                                               const float* __restrict__ cvec,
                                               float4* __restrict__ Sout4, int N, int last) {
  int node = blockIdx.x * 64 + (threadIdx.x >> 2);
  int o = threadIdx.x & 3;
  if (node >= N) return;
  float4 z = Sin4[(size_t)node * 4 + o];
  float ax = z.x, ay = z.y, az = z.z, aw = z.w;
  int j = roff[node], e = roff[node + 1];
  for (; j + 3 < e; j += 4) {
    int s0 = col[j], s1 = col[j + 1], s2 = col[j + 2], s3 = col[j + 3];
    float4 v0 = Sin4[(size_t)s0 * 4 + o];
    float4 v1 = Sin4[(size_t)s1 * 4 + o];
    float4 v2 = Sin4[(size_t)s2 * 4 + o];
    float4 v3 = Sin4[(size_t)s3 * 4 + o];
    ax += v0.x + v1.x + v2.x + v3.x;
    ay += v0.y + v1.y + v2.y + v3.y;
    az += v0.z + v1.z + v2.z + v3.z;
    aw += v0.w + v1.w + v2.w + v3.w;
  }
  for (; j < e; j++) {
    float4 v0 = Sin4[(size_t)col[j] * 4 + o];
    ax += v0.x; ay += v0.y; az += v0.z; aw += v0.w;
  }
  float di = dinv[node];
  float sg = last ? di : di * di;
  float sc = last ? 1.f : di;
  float4 cv = ((const float4*)cvec)[o];
  Sout4[(size_t)node * 4 + o] =
      make_float4(sg * ax + sc * cv.x, sg * ay + sc * cv.y,
                  sg * az + sc * cv.z, sg * aw + sc * cv.w);
}

// ---------------- Pooling + bias (gbounds inlined) ----------------

__global__ __launch_bounds__(128) void k_pool(const float* __restrict__ Z,
                                              const int* __restrict__ batch,
                                              const float* __restrict__ b_out,
                                              float* __restrict__ out, int N, int G) {
  __shared__ float red[8][16];
  __shared__ int bounds[2];
  int g = blockIdx.x;
  int t = threadIdx.x;
  if (t < 2) {
    int target = g + t;
    int lo = 0, hi = N;
    while (lo < hi) {
      int mid = (lo + hi) >> 1;
      if (batch[mid] < target) lo = mid + 1; else hi = mid;
    }
    bounds[t] = lo;
  }
  __syncthreads();
  int s = bounds[0], e = bounds[1];
  int f = t & 15, c = t >> 4;
  float acc = 0.f;
  for (int n = s + c; n < e; n += 8) acc += Z[(size_t)n * 16 + f];
  red[c][f] = acc;
  __syncthreads();
  if (c == 0 && f < 10) {
    float a = 0.f;
#pragma unroll
    for (int i = 0; i < 8; i++) a += red[i][f];
    out[g * 10 + f] = a / fmaxf((float)(e - s), 1.f) + b_out[f];
  }
}

// ---------------- launch ----------------

extern "C" void kernel_launch(void* const* d_in, const int* in_sizes, int n_in,
                              void* d_out, int out_size, void* d_ws, size_t ws_size,
                              hipStream_t stream) {
  const float* x     = (const float*)d_in[0];
  const int*   eidx  = (const int*)d_in[1];
  const int*   batch = (const int*)d_in[2];
  const float* W_in  = (const float*)d_in[3];
  const float* b_in  = (const float*)d_in[4];
  const float* W_hid = (const float*)d_in[5];
  const float* b_hid = (const float*)d_in[6];
  const float* W_out = (const float*)d_in[7];
  const float* b_out = (const float*)d_in[8];

  const int N = in_sizes[0] / 128;
  const int E = in_sizes[1] / 2;
  const int G = out_size / 10;

  const int* src = eidx;
  const int* dst = eidx + E;

  const int NB = (N + 127) >> BK_SHIFT;
  const int NBLK = (E + CHUNK - 1) / CHUNK;

  char* ws = (char*)d_ws;
  size_t off = 0;
  auto alloc = [&](size_t b) {
    char* p = ws + off;
    off = (off + b + 255) & ~(size_t)255;
    return p;
  };
  unsigned* staging = (unsigned*)alloc((size_t)E * 4);
  int*   col     = (int*)alloc((size_t)E * 4);
  int*   blkcnt  = (int*)alloc((size_t)NB * NBLK * 4);
  int*   btot    = (int*)alloc((size_t)NB * 4);
  int*   bbase   = (int*)alloc((size_t)(NB + 1) * 4);
  int*   roff    = (int*)alloc((size_t)(N + 1) * 4);
  float* dinv    = (float*)alloc((size_t)N * 4);
  float* stateA  = (float*)alloc((size_t)N * 16 * 4);
  float* stateB  = (float*)alloc((size_t)N * 16 * 4);
  float* ppA     = (float*)alloc(128 * 16 * 4);
  float* ppB     = (float*)alloc(128 * 16 * 4);
  float* Y16     = (float*)alloc(128 * 16 * 4);
  float* cvec    = (float*)alloc(4 * 16 * 4);
  (void)ws_size; (void)n_in;

  // Weight chain as 4 small GEMM stages (each emits its chain-bias term)
  k_stage<<<8, 256, 0, stream>>>(W_hid + 2 * 16384, W_out, 10, b_hid + 2 * 128, cvec + 48, ppA);
  k_stage<<<8, 256, 0, stream>>>(W_hid + 1 * 16384, ppA, 16, b_hid + 1 * 128, cvec + 32, ppB);
  k_stage<<<8, 256, 0, stream>>>(W_hid + 0 * 16384, ppB, 16, b_hid + 0 * 128, cvec + 16, ppA);
  k_stage<<<8, 256, 0, stream>>>(W_in, ppA, 16, b_in, cvec + 0, Y16);

  // Bucketed CSR build (no global atomics, no fences)
  k_bucket_count<<<NBLK, 256, 0, stream>>>(dst, blkcnt, E, NB, NBLK);
  k_bucket_scanB<<<NB, 256, 0, stream>>>(blkcnt, btot, NBLK);
  k_bucket_base<<<1, 1024, 0, stream>>>(btot, bbase, NB);
  k_bucket_scatter<<<NBLK, 256, 0, stream>>>(src, dst, blkcnt, bbase, staging, E, NB, NBLK);
  k_csr_build<<<NB, 256, 0, stream>>>(staging, bbase, roff, dinv, col, N, NB, E);

  // S0 = dinv * (X @ Y)
  k_xy<<<(N + 127) / 128, 256, 0, stream>>>(x, Y16, dinv, stateA, N);

  // 4 unweighted gather passes on scaled state
  float* zi = stateA;
  float* zo = stateB;
  for (int l = 0; l < 4; l++) {
    k_agg10<<<(N + 63) / 64, 256, 0, stream>>>((const float4*)zi, col, roff, dinv,
                                               cvec + 16 * l, (float4*)zo, N, (l == 3) ? 1 : 0);
    float* t = zi; zi = zo; zo = t;
  }

  k_pool<<<G, 128, 0, stream>>>(zi, batch, b_out, (float*)d_out, N, G);
}

// Round 13
// 283.597 us; speedup vs baseline: 2.2078x; 1.0104x over previous
//
#include <hip/hip_runtime.h>

#define BK_SHIFT 7
#define NB_MAX 1024
#define CHUNK 8192

typedef int i4u __attribute__((ext_vector_type(4), aligned(4)));

// ---------------- Bucketed CSR build (no global atomics) ----------------

// Pass A: per-block bucket histogram (bucket = dst >> 7), int4-vectorized.
__global__ __launch_bounds__(256) void k_bucket_count(const int* __restrict__ dst,
                                                      int* __restrict__ blkcnt,
                                                      int E, int NB, int NBLK) {
  __shared__ int cnt[NB_MAX];
  int t = threadIdx.x, b = blockIdx.x;
  for (int i = t; i < NB; i += 256) cnt[i] = 0;
  __syncthreads();
  int e0 = b * CHUNK, e1 = min(E, e0 + CHUNK);
  if (e1 - e0 == CHUNK) {
    const int4* d4 = (const int4*)(dst + e0);
#pragma unroll 2
    for (int i = t; i < CHUNK / 4; i += 256) {
      int4 v = d4[i];
      atomicAdd(&cnt[v.x >> BK_SHIFT], 1);
      atomicAdd(&cnt[v.y >> BK_SHIFT], 1);
      atomicAdd(&cnt[v.z >> BK_SHIFT], 1);
      atomicAdd(&cnt[v.w >> BK_SHIFT], 1);
    }
  } else {
    for (int e = e0 + t; e < e1; e += 256) atomicAdd(&cnt[dst[e] >> BK_SHIFT], 1);
  }
  __syncthreads();
  for (int i = t; i < NB; i += 256) blkcnt[(size_t)i * NBLK + b] = cnt[i];
}

// Pass B: per-bucket exclusive scan across blocks (in place), bucket totals out.
__global__ __launch_bounds__(256) void k_bucket_scanB(int* __restrict__ blkcnt,
                                                      int* __restrict__ btot, int NBLK) {
  __shared__ int v[256];
  int t = threadIdx.x, k = blockIdx.x;
  int x = (t < NBLK) ? blkcnt[(size_t)k * NBLK + t] : 0;
  v[t] = x;
  __syncthreads();
  for (int off = 1; off < 256; off <<= 1) {
    int u = (t >= off) ? v[t - off] : 0;
    __syncthreads();
    v[t] += u;
    __syncthreads();
  }
  if (t < NBLK) blkcnt[(size_t)k * NBLK + t] = v[t] - x;  // exclusive
  if (t == 255) btot[k] = v[255];
}

// Pass B2: exclusive scan over bucket totals -> bucket base offsets
__global__ __launch_bounds__(1024) void k_bucket_base(const int* __restrict__ btot,
                                                      int* __restrict__ bbase, int NB) {
  __shared__ int v[1024];
  int t = threadIdx.x;
  int x = (t < NB) ? btot[t] : 0;
  v[t] = x;
  __syncthreads();
  for (int off = 1; off < 1024; off <<= 1) {
    int u = (t >= off) ? v[t - off] : 0;
    __syncthreads();
    v[t] += u;
    __syncthreads();
  }
  if (t < NB) bbase[t] = v[t] - x;
  if (t == 1023) bbase[NB] = v[1023];
}

// Pass C: LDS-sorted scatter (dense write runs).
__global__ __launch_bounds__(256) void k_bucket_scatter(const int* __restrict__ src,
                                                        const int* __restrict__ dst,
                                                        const int* __restrict__ blkoff,
                                                        const int* __restrict__ bbase,
                                                        unsigned* __restrict__ staging,
                                                        int E, int NB, int NBLK) {
  __shared__ unsigned sval[CHUNK];
  __shared__ int ga0[CHUNK];
  __shared__ int lcnt[NB_MAX];
  __shared__ int gofs[NB_MAX];
  __shared__ int curs[NB_MAX];
  __shared__ int v[256];
  int t = threadIdx.x, b = blockIdx.x;
  for (int i = t; i < NB; i += 256) lcnt[i] = 0;
  __syncthreads();
  int e0 = b * CHUNK, e1 = min(E, e0 + CHUNK);
  int chunkE = e1 - e0;
  if (chunkE == CHUNK) {
    const int4* d4 = (const int4*)(dst + e0);
#pragma unroll 2
    for (int i = t; i < CHUNK / 4; i += 256) {
      int4 w = d4[i];
      atomicAdd(&lcnt[w.x >> BK_SHIFT], 1);
      atomicAdd(&lcnt[w.y >> BK_SHIFT], 1);
      atomicAdd(&lcnt[w.z >> BK_SHIFT], 1);
      atomicAdd(&lcnt[w.w >> BK_SHIFT], 1);
    }
  } else {
    for (int e = e0 + t; e < e1; e += 256) atomicAdd(&lcnt[dst[e] >> BK_SHIFT], 1);
  }
  __syncthreads();
  int base4 = t * 4;
  int a0 = (base4 + 0 < NB) ? lcnt[base4 + 0] : 0;
  int a1 = (base4 + 1 < NB) ? lcnt[base4 + 1] : 0;
  int a2 = (base4 + 2 < NB) ? lcnt[base4 + 2] : 0;
  int a3 = (base4 + 3 < NB) ? lcnt[base4 + 3] : 0;
  int s = a0 + a1 + a2 + a3;
  v[t] = s;
  __syncthreads();
  for (int off = 1; off < 256; off <<= 1) {
    int u = (t >= off) ? v[t - off] : 0;
    __syncthreads();
    v[t] += u;
    __syncthreads();
  }
  int run = v[t] - s;  // exclusive
  {
    int aa[4] = {a0, a1, a2, a3};
#pragma unroll
    for (int i = 0; i < 4; i++) {
      int bk = base4 + i;
      if (bk < NB) {
        gofs[bk] = bbase[bk] + blkoff[(size_t)bk * NBLK + b] - run;
        curs[bk] = run;
        run += aa[i];
      }
    }
  }
  __syncthreads();
  for (int e = e0 + t; e < e1; e += 256) {
    int d = dst[e];
    int sidx = src[e];
    int bk = d >> BK_SHIFT;
    int slot = atomicAdd(&curs[bk], 1);
    sval[slot] = ((unsigned)(d & 127) << 25) | (unsigned)sidx;
    ga0[slot] = gofs[bk];
  }
  __syncthreads();
  for (int i = t; i < chunkE; i += 256) staging[ga0[i] + i] = sval[i];
}

// Pass D: per-bucket counts -> dinv + roff (dense), then in-bucket scatter of col
__global__ __launch_bounds__(256) void k_csr_build(const unsigned* __restrict__ staging,
                                                   const int* __restrict__ bbase,
                                                   int* __restrict__ roff,
                                                   float* __restrict__ dinv,
                                                   int* __restrict__ col,
                                                   int N, int NB, int E) {
  __shared__ int cnt[128];
  __shared__ int sa[128], sb[128];
  __shared__ int cursor[128];
  int t = threadIdx.x, k = blockIdx.x;
  int node0 = k << BK_SHIFT;
  int nNodes = min(128, N - node0);
  int e0 = bbase[k], e1 = bbase[k + 1];
  if (t < 128) cnt[t] = 0;
  __syncthreads();
  for (int e = e0 + t; e < e1; e += 256) atomicAdd(&cnt[staging[e] >> 25], 1);
  __syncthreads();
  int* a = sa;
  int* bq = sb;
  if (t < 128) a[t] = cnt[t];
  __syncthreads();
  for (int off = 1; off < 128; off <<= 1) {
    if (t < 128) bq[t] = (t >= off) ? a[t] + a[t - off] : a[t];
    __syncthreads();
    int* tmp = a; a = bq; bq = tmp;
  }
  if (t < 128) {
    int excl = e0 + ((t > 0) ? a[t - 1] : 0);
    cursor[t] = excl;
    if (t < nNodes) {
      roff[node0 + t] = excl;
      dinv[node0 + t] = rsqrtf((float)(cnt[t] + 1));  // +1 = self loop
    }
  }
  if (k == NB - 1 && t == 0) roff[N] = E;
  __syncthreads();
  for (int e = e0 + t; e < e1; e += 256) {
    unsigned p = staging[e];
    int slot = atomicAdd(&cursor[p >> 25], 1);
    col[slot] = (int)(p & 0x01FFFFFFu);
  }
}

// ---------------- Weight-chain stage: C(128x16) = W(128x128) @ B(128x{10|16}) ----

__global__ __launch_bounds__(256) void k_stage(const float* __restrict__ W,
                                               const float* __restrict__ Bsrc, int bcols,
                                               const float* __restrict__ bias,
                                               float* __restrict__ cvec_out,
                                               float* __restrict__ Cout) {
  __shared__ float Ws[16][129];
  __shared__ float Bs[128][17];
  int t = threadIdx.x;
  int r0 = blockIdx.x * 16;
  for (int i = t; i < 2048; i += 256) {
    int k = i >> 4, o = i & 15;
    Bs[k][o] = (o < bcols) ? Bsrc[k * bcols + o] : 0.f;
  }
  for (int i = t; i < 2048; i += 256) {
    int r = i >> 7, c = i & 127;
    Ws[r][c] = W[(size_t)(r0 + r) * 128 + c];
  }
  __syncthreads();
  if (blockIdx.x == 0 && t < 16) {
    float a = 0.f;
    for (int k = 0; k < 128; k++) a += bias[k] * Bs[k][t];
    cvec_out[t] = a;
  }
  int row = t >> 4, o = t & 15;
  float acc = 0.f;
#pragma unroll 8
  for (int k = 0; k < 128; k++) acc += Ws[row][k] * Bs[k][o];
  Cout[(size_t)(r0 + row) * 16 + o] = acc;
}

// ---------------- S0 = dinv * (X @ Y16): LDS-tiled skinny GEMM ----------------

__global__ __launch_bounds__(256) void k_xy(const float* __restrict__ X,
                                            const float* __restrict__ Y16,
                                            const float* __restrict__ dinv,
                                            float* __restrict__ S, int N) {
  __shared__ float Xs[128][132];
  __shared__ float Yt[16][132];  // Yt[o][k]
  int t = threadIdx.x;
  int n0 = blockIdx.x * 128;
  for (int i = t; i < 2048; i += 256) {
    int k = i >> 4, o = i & 15;
    Yt[o][k] = Y16[k * 16 + o];
  }
#pragma unroll
  for (int it = 0; it < 16; it++) {
    int idx = t + it * 256;
    int r = idx >> 5;
    int c4 = idx & 31;
    int row = n0 + r;
    float4 v = *(const float4*)&X[(size_t)(row < N ? row : 0) * 128 + c4 * 4];
    *(float4*)&Xs[r][c4 * 4] = v;
  }
  __syncthreads();
  int cp = t & 7;
  int q = t >> 3;
  float acc[4][2];
#pragma unroll
  for (int i = 0; i < 4; i++) { acc[i][0] = 0.f; acc[i][1] = 0.f; }
  const float4* y0r = (const float4*)&Yt[2 * cp][0];
  const float4* y1r = (const float4*)&Yt[2 * cp + 1][0];
#pragma unroll 4
  for (int k4 = 0; k4 < 32; k4++) {
    float4 y0 = y0r[k4];
    float4 y1 = y1r[k4];
#pragma unroll
    for (int i = 0; i < 4; i++) {
      float4 xv = *(const float4*)&Xs[q + 32 * i][k4 * 4];
      acc[i][0] += xv.x * y0.x + xv.y * y0.y + xv.z * y0.z + xv.w * y0.w;
      acc[i][1] += xv.x * y1.x + xv.y * y1.y + xv.z * y1.z + xv.w * y1.w;
    }
  }
#pragma unroll
  for (int i = 0; i < 4; i++) {
    int node = n0 + q + 32 * i;
    if (node < N) {
      float di = dinv[node];
      *(float2*)&S[(size_t)node * 16 + 2 * cp] =
          make_float2(acc[i][0] * di, acc[i][1] * di);
    }
  }
}

// ---------------- Aggregation on scaled state (16-wide, 4 lanes/node) ----------------
// int4 col loads (4-B aligned dwordx4 is legal on gfx950): 5 VMEM instrs per
// 4 edges instead of 8. Last pass skips the o==3 store (cols 12-15 unread).

__global__ __launch_bounds__(256) void k_agg10(const float4* __restrict__ Sin4,
                                               const int* __restrict__ col,
                                               const int* __restrict__ roff,
                                               const float* __restrict__ dinv,
                                               const float* __restrict__ cvec,
                                               float4* __restrict__ Sout4, int N, int last) {
  int node = blockIdx.x * 64 + (threadIdx.x >> 2);
  int o = threadIdx.x & 3;
  if (node >= N) return;
  float4 z = Sin4[(size_t)node * 4 + o];
  float ax = z.x, ay = z.y, az = z.z, aw = z.w;
  int j = roff[node], e = roff[node + 1];
  for (; j + 3 < e; j += 4) {
    i4u c = *(const i4u*)(col + j);
    float4 v0 = Sin4[(size_t)c.x * 4 + o];
    float4 v1 = Sin4[(size_t)c.y * 4 + o];
    float4 v2 = Sin4[(size_t)c.z * 4 + o];
    float4 v3 = Sin4[(size_t)c.w * 4 + o];
    ax += v0.x + v1.x + v2.x + v3.x;
    ay += v0.y + v1.y + v2.y + v3.y;
    az += v0.z + v1.z + v2.z + v3.z;
    aw += v0.w + v1.w + v2.w + v3.w;
  }
  for (; j < e; j++) {
    float4 v0 = Sin4[(size_t)col[j] * 4 + o];
    ax += v0.x; ay += v0.y; az += v0.z; aw += v0.w;
  }
  if (last && o == 3) return;  // cols 12-15 are pad; nobody reads them
  float di = dinv[node];
  float sg = last ? di : di * di;
  float sc = last ? 1.f : di;
  float4 cv = ((const float4*)cvec)[o];
  Sout4[(size_t)node * 4 + o] =
      make_float4(sg * ax + sc * cv.x, sg * ay + sc * cv.y,
                  sg * az + sc * cv.z, sg * aw + sc * cv.w);
}

// ---------------- Pooling + bias (gbounds inlined) ----------------

__global__ __launch_bounds__(128) void k_pool(const float* __restrict__ Z,
                                              const int* __restrict__ batch,
                                              const float* __restrict__ b_out,
                                              float* __restrict__ out, int N, int G) {
  __shared__ float red[8][16];
  __shared__ int bounds[2];
  int g = blockIdx.x;
  int t = threadIdx.x;
  if (t < 2) {
    int target = g + t;
    int lo = 0, hi = N;
    while (lo < hi) {
      int mid = (lo + hi) >> 1;
      if (batch[mid] < target) lo = mid + 1; else hi = mid;
    }
    bounds[t] = lo;
  }
  __syncthreads();
  int s = bounds[0], e = bounds[1];
  int f = t & 15, c = t >> 4;
  float acc = 0.f;
  if (f < 10) {
    for (int n = s + c; n < e; n += 8) acc += Z[(size_t)n * 16 + f];
  }
  red[c][f] = acc;
  __syncthreads();
  if (c == 0 && f < 10) {
    float a = 0.f;
#pragma unroll
    for (int i = 0; i < 8; i++) a += red[i][f];
    out[g * 10 + f] = a / fmaxf((float)(e - s), 1.f) + b_out[f];
  }
}

// ---------------- launch ----------------

extern "C" void kernel_launch(void* const* d_in, const int* in_sizes, int n_in,
                              void* d_out, int out_size, void* d_ws, size_t ws_size,
                              hipStream_t stream) {
  const float* x     = (const float*)d_in[0];
  const int*   eidx  = (const int*)d_in[1];
  const int*   batch = (const int*)d_in[2];
  const float* W_in  = (const float*)d_in[3];
  const float* b_in  = (const float*)d_in[4];
  const float* W_hid = (const float*)d_in[5];
  const float* b_hid = (const float*)d_in[6];
  const float* W_out = (const float*)d_in[7];
  const float* b_out = (const float*)d_in[8];

  const int N = in_sizes[0] / 128;
  const int E = in_sizes[1] / 2;
  const int G = out_size / 10;

  const int* src = eidx;
  const int* dst = eidx + E;

  const int NB = (N + 127) >> BK_SHIFT;
  const int NBLK = (E + CHUNK - 1) / CHUNK;

  char* ws = (char*)d_ws;
  size_t off = 0;
  auto alloc = [&](size_t b) {
    char* p = ws + off;
    off = (off + b + 255) & ~(size_t)255;
    return p;
  };
  unsigned* staging = (unsigned*)alloc((size_t)E * 4);
  int*   col     = (int*)alloc((size_t)E * 4 + 16);
  int*   blkcnt  = (int*)alloc((size_t)NB * NBLK * 4);
  int*   btot    = (int*)alloc((size_t)NB * 4);
  int*   bbase   = (int*)alloc((size_t)(NB + 1) * 4);
  int*   roff    = (int*)alloc((size_t)(N + 1) * 4);
  float* dinv    = (float*)alloc((size_t)N * 4);
  float* stateA  = (float*)alloc((size_t)N * 16 * 4);
  float* stateB  = (float*)alloc((size_t)N * 16 * 4);
  float* ppA     = (float*)alloc(128 * 16 * 4);
  float* ppB     = (float*)alloc(128 * 16 * 4);
  float* Y16     = (float*)alloc(128 * 16 * 4);
  float* cvec    = (float*)alloc(4 * 16 * 4);
  (void)ws_size; (void)n_in;

  // Weight chain as 4 small GEMM stages (each emits its chain-bias term)
  k_stage<<<8, 256, 0, stream>>>(W_hid + 2 * 16384, W_out, 10, b_hid + 2 * 128, cvec + 48, ppA);
  k_stage<<<8, 256, 0, stream>>>(W_hid + 1 * 16384, ppA, 16, b_hid + 1 * 128, cvec + 32, ppB);
  k_stage<<<8, 256, 0, stream>>>(W_hid + 0 * 16384, ppB, 16, b_hid + 0 * 128, cvec + 16, ppA);
  k_stage<<<8, 256, 0, stream>>>(W_in, ppA, 16, b_in, cvec + 0, Y16);

  // Bucketed CSR build (no global atomics, no fences)
  k_bucket_count<<<NBLK, 256, 0, stream>>>(dst, blkcnt, E, NB, NBLK);
  k_bucket_scanB<<<NB, 256, 0, stream>>>(blkcnt, btot, NBLK);
  k_bucket_base<<<1, 1024, 0, stream>>>(btot, bbase, NB);
  k_bucket_scatter<<<NBLK, 256, 0, stream>>>(src, dst, blkcnt, bbase, staging, E, NB, NBLK);
  k_csr_build<<<NB, 256, 0, stream>>>(staging, bbase, roff, dinv, col, N, NB, E);

  // S0 = dinv * (X @ Y)
  k_xy<<<(N + 127) / 128, 256, 0, stream>>>(x, Y16, dinv, stateA, N);

  // 4 unweighted gather passes on scaled state
  float* zi = stateA;
  float* zo = stateB;
  for (int l = 0; l < 4; l++) {
    k_agg10<<<(N + 63) / 64, 256, 0, stream>>>((const float4*)zi, col, roff, dinv,
                                               cvec + 16 * l, (float4*)zo, N, (l == 3) ? 1 : 0);
    float* t = zi; zi = zo; zo = t;
  }

  k_pool<<<G, 128, 0, stream>>>(zi, batch, b_out, (float*)d_out, N, G);
}